// Round 10
// baseline (225.207 us; speedup 1.0000x reference)
//
#include <hip/hip_runtime.h>

namespace {
constexpr int Hn = 512, Wn = 512;
constexpr int WHn = 227, WWn = 227;
constexpr int OHn = Hn - WHn;        // 285
constexpr int OWn = Wn - WWn;        // 285
constexpr int PTn = 113, PLn = 113;  // replicate-pad offsets
constexpr float EPSn = 1e-5f;
typedef float floatx4 __attribute__((ext_vector_type(4)));  // NT-store-able
}

// Fully fused LocalContextNorm. One block per (group, chunk). 512 threads.
// Round-10 = round-9 with the NT-store type fixed (ext_vector float4).
//  * All out-writes are NON-TEMPORAL: out is never re-read, and keeping it
//    out of L2/L3 preserves x (256 MB, L3-resident) -> re-reads hit cache.
//  * Slide prefetch issued AFTER bar2: no barrier between issue and
//    consumption, so the s_waitcnt vmcnt(0) before s_barrier no longer
//    force-drains the pipeline (only xa crosses bar1).
// Phase A: ramp = flat float4 stream of rows h0+1..h0+227 (both channels),
//          LDS-transposed to per-column (S,Q) window sums.
// Phase B: per 8 stat rows: f32 vertical slide + 512-wide scan -> window
//          sums in Ps[buf]; normalize out rows hh = sh+113 directly.
// Phase C: chunk 0 streams border rows 0..112 (stat row 0), chunk 3 rows
//          398..511 (stat row 284), stats via bstat LDS.
// Chunk split {48,96,96,45} balances border-duty blocks.
// Window for stat (h,w): input rows h+1..h+227, cols w+1..w+227.
__global__ __launch_bounds__(512, 4) void lcn_fused(const float* __restrict__ x,
                                                    const float* __restrict__ weight,
                                                    const float* __restrict__ bias,
                                                    float* __restrict__ out) {
  const int B = blockIdx.x;
  const int X = B & 7;               // XCD (round-robin heuristic)
  const int s = B >> 3;
  const int chunk = s & 3;
  const int g = X * 16 + (s >> 2);   // 0..127 global group; chunks co-XCD
  const int w = threadIdx.x;
  const int lane = w & 63;
  const int wid = w >> 6;

  const float* __restrict__ x0 = x + (size_t)(g * 2) * Hn * Wn;
  const float* __restrict__ x1 = x0 + (size_t)Hn * Wn;
  float* __restrict__ o0 = out + (size_t)(g * 2) * Hn * Wn;
  float* __restrict__ o1 = o0 + (size_t)Hn * Wn;
  // weight/bias: 32 entries, index by channel within image (round-6 bug).
  const int cch = (g & 15) * 2;
  const float wt0 = weight[cch], wt1 = weight[cch + 1];
  const float bs0 = bias[cch], bs1 = bias[cch + 1];

  const int h0 = chunk == 0 ? 0 : chunk == 1 ? 48 : chunk == 2 ? 144 : 240;
  const int h1 = chunk == 0 ? 48 : chunk == 1 ? 144 : chunk == 2 ? 240 : 285;

  __shared__ __align__(16) float2 Ps[2][8][Wn + 1];  // double-buffered scans
  __shared__ float2 wsum[8][8];
  __shared__ float2 bstat[4][132];   // border stats, transposed [j][quad]

  // ---- Phase A: ramp as flat float4 stream, 16 loads in flight ----
  const int q = w & 127;             // column quad: cols 4q..4q+3
  const int p = w >> 7;              // row phase 0..3
  float4 sS = {0.f, 0.f, 0.f, 0.f}, sQ = {0.f, 0.f, 0.f, 0.f};
  {
    const float4* __restrict__ r0 =
        reinterpret_cast<const float4*>(x0 + (size_t)(h0 + 1) * Wn) + q;
    const float4* __restrict__ r1 =
        reinterpret_cast<const float4*>(x1 + (size_t)(h0 + 1) * Wn) + q;
    #pragma unroll 8
    for (int r = p; r < WHn; r += 4) {
      float4 a = r0[(size_t)r * (Wn / 4)];
      float4 b = r1[(size_t)r * (Wn / 4)];
      sS.x += a.x + b.x; sQ.x += a.x * a.x + b.x * b.x;
      sS.y += a.y + b.y; sQ.y += a.y * a.y + b.y * b.y;
      sS.z += a.z + b.z; sQ.z += a.z * a.z + b.z * b.z;
      sS.w += a.w + b.w; sQ.w += a.w * a.w + b.w * b.w;
    }
  }
  float accS, accQ;
  {
    float4* cc = reinterpret_cast<float4*>(&Ps[0][0][0]);   // [4][256] float4
    cc[p * 256 + 2 * q]     = make_float4(sS.x, sQ.x, sS.y, sQ.y);
    cc[p * 256 + 2 * q + 1] = make_float4(sS.z, sQ.z, sS.w, sQ.w);
    __syncthreads();
    const float2* cf = reinterpret_cast<const float2*>(&Ps[0][0][0]); // [4][512]
    float2 t0 = cf[0 * Wn + w], t1 = cf[1 * Wn + w];
    float2 t2 = cf[2 * Wn + w], t3 = cf[3 * Wn + w];
    accS = (t0.x + t1.x) + (t2.x + t3.x);
    accQ = (t0.y + t1.y) + (t2.y + t3.y);
    __syncthreads();   // Ps free for scan reuse
  }

  const float inv_n = 1.0f / (float)(WHn * WWn * 2);
  const int wp = min(max(w - PLn, 0), OWn - 1);   // out-col -> stat-col

  // slide prefetch: add rows h+228+j, sub rows h+1+j (j=0..7), 2 channels
  float pa0[8], pa1[8], ps0[8], ps1[8];
  auto prefetch = [&](int hb) {
    #pragma unroll
    for (int j = 0; j < 8; ++j) {
      int ra = min(hb + WHn + 1 + j, Hn - 1);   // clamp: guarded rows unused
      int rs = hb + 1 + j;                      // max 281+7=288 < 512
      pa0[j] = x0[(size_t)ra * Wn + w];
      pa1[j] = x1[(size_t)ra * Wn + w];
      ps0[j] = x0[(size_t)rs * Wn + w];
      ps1[j] = x1[(size_t)rs * Wn + w];
    }
  };
  prefetch(h0);

  // ---- Phase B: slide + scan + fused normalize, 8 rows/iter ----
  int buf = 0;
  for (int h = h0; h < h1; h += 8) {
    // consume slide regs (issued post-bar2 of previous iter: no barrier
    // crossed between issue and this use)
    float2 v[8];
    v[0] = make_float2(accS, accQ);
    float s2 = accS, q2 = accQ;
    #pragma unroll
    for (int j = 0; j < 7; ++j) {
      s2 += (pa0[j] + pa1[j]) - (ps0[j] + ps1[j]);
      q2 += (pa0[j] * pa0[j] + pa1[j] * pa1[j])
          - (ps0[j] * ps0[j] + ps1[j] * ps1[j]);
      v[j + 1] = make_float2(s2, q2);
    }
    s2 += (pa0[7] + pa1[7]) - (ps0[7] + ps1[7]);
    q2 += (pa0[7] * pa0[7] + pa1[7] * pa1[7])
        - (ps0[7] * ps0[7] + ps1[7] * ps1[7]);
    accS = s2; accQ = q2;

    // this iteration's norm-x loads: flight = scan + bar1 + fixup + bar2
    float xa[8], xb[8];
    #pragma unroll
    for (int rr = 0; rr < 8; ++rr) {
      const size_t hh = (size_t)(h + PTn + rr) * Wn + w;  // max row 400 < 512
      xa[rr] = x0[hh];
      xb[rr] = x1[hh];
    }

    // 8 independent 512-wide inclusive scans (shared barriers)
    #pragma unroll
    for (int d = 1; d < 64; d <<= 1) {
      #pragma unroll
      for (int rr = 0; rr < 8; ++rr) {
        float sx = __shfl_up(v[rr].x, d, 64);
        float sy = __shfl_up(v[rr].y, d, 64);
        if (lane >= d) { v[rr].x += sx; v[rr].y += sy; }
      }
    }
    if (lane == 63) {
      #pragma unroll
      for (int rr = 0; rr < 8; ++rr) wsum[wid][rr] = v[rr];
    }
    __syncthreads();
    float2 off[8] = {{0.f,0.f},{0.f,0.f},{0.f,0.f},{0.f,0.f},
                     {0.f,0.f},{0.f,0.f},{0.f,0.f},{0.f,0.f}};
    #pragma unroll
    for (int i = 0; i < 7; ++i) {
      if (i < wid) {
        #pragma unroll
        for (int rr = 0; rr < 8; ++rr) {
          off[rr].x += wsum[i][rr].x; off[rr].y += wsum[i][rr].y;
        }
      }
    }
    #pragma unroll
    for (int rr = 0; rr < 8; ++rr)
      Ps[buf][rr][w + 1] = make_float2(v[rr].x + off[rr].x, v[rr].y + off[rr].y);
    __syncthreads();

    // issue NEXT iteration's slide loads now: no barrier between here and
    // their consumption; norm below covers their latency.
    if (h + 8 < h1) prefetch(h + 8);

    // fused normalize: out row hh = (h+rr)+113 from stat row h+rr.
    #pragma unroll
    for (int rr = 0; rr < 8; ++rr) {
      if (h + rr < h1) {
        float2 hi = Ps[buf][rr][wp + WWn + 1];
        float2 lo = Ps[buf][rr][wp + 1];
        float S = hi.x - lo.x;
        float Q = hi.y - lo.y;
        float mean = S * inv_n;
        float var = (Q - S * S * inv_n) * inv_n;
        float istd = rsqrtf(var + EPSn);
        if ((chunk == 0 && h + rr == 0) || (chunk == 3 && h + rr == 284))
          bstat[w & 3][w >> 2] = make_float2(mean, istd);
        const size_t oo = (size_t)(h + PTn + rr) * Wn + w;
        __builtin_nontemporal_store((xa[rr] - mean) * istd * wt0 + bs0, &o0[oo]);
        __builtin_nontemporal_store((xb[rr] - mean) * istd * wt1 + bs1, &o1[oo]);
      }
    }
    buf ^= 1;
  }

  // ---- Phase C: replicate-pad border rows (chunk 0: 0..112, chunk 3: 398..511)
  if (chunk == 0 || chunk == 3) {
    __syncthreads();   // bstat visibility across threads
    const int row0 = (chunk == 0) ? 0 : 398;
    const int nrows = (chunk == 0) ? PTn : Hn - 398;   // 113 / 114
    const int total = nrows * 256;                     // 2 ch x 128 quads
    const float4* __restrict__ xf0 = reinterpret_cast<const float4*>(x0);
    const float4* __restrict__ xf1 = reinterpret_cast<const float4*>(x1);
    floatx4* __restrict__ of0 = reinterpret_cast<floatx4*>(o0);
    floatx4* __restrict__ of1 = reinterpret_cast<floatx4*>(o1);
    for (int i = w; i < total; i += 512) {
      const int qq = i & 127;
      const int ch = (i >> 7) & 1;
      const int row = row0 + (i >> 8);
      const size_t idx = (size_t)row * (Wn / 4) + qq;
      const float4 xv = ch ? xf1[idx] : xf0[idx];
      const float wt = ch ? wt1 : wt0;
      const float bsv = ch ? bs1 : bs0;
      const float2 m0 = bstat[0][qq];
      const float2 m1 = bstat[1][qq];
      const float2 m2 = bstat[2][qq];
      const float2 m3 = bstat[3][qq];
      floatx4 ov;
      ov.x = (xv.x - m0.x) * m0.y * wt + bsv;
      ov.y = (xv.y - m1.x) * m1.y * wt + bsv;
      ov.z = (xv.z - m2.x) * m2.y * wt + bsv;
      ov.w = (xv.w - m3.x) * m3.y * wt + bsv;
      if (ch) __builtin_nontemporal_store(ov, &of1[idx]);
      else    __builtin_nontemporal_store(ov, &of0[idx]);
    }
  }
}

extern "C" void kernel_launch(void* const* d_in, const int* in_sizes, int n_in,
                              void* d_out, int out_size, void* d_ws, size_t ws_size,
                              hipStream_t stream) {
  const float* x = (const float*)d_in[0];
  const float* weight = (const float*)d_in[1];
  const float* bias = (const float*)d_in[2];
  float* out = (float*)d_out;

  hipLaunchKernelGGL(lcn_fused, dim3(128 * 4), dim3(512), 0, stream,
                     x, weight, bias, out);
}

// Round 11
// 196.413 us; speedup vs baseline: 1.1466x; 1.1466x over previous
//
#include <hip/hip_runtime.h>

namespace {
constexpr int Hn = 512, Wn = 512;
constexpr int WHn = 227, WWn = 227;
constexpr int OHn = Hn - WHn;        // 285
constexpr int OWn = Wn - WWn;        // 285
constexpr int PTn = 113, PLn = 113;  // replicate-pad offsets
constexpr float EPSn = 1e-5f;
// chunk row-splits {46,97,97,45}: border-duty chunks (0,3) get fewer rows
__device__ __constant__ int kH0[4] = {0, 46, 143, 240};
__device__ __constant__ int kH1[4] = {46, 143, 240, 285};
// 7 disjoint row segments whose sums compose all 4 chunk-start windows
// window(h0) = rows h0+1..h0+227:
//  w(0)=A+B+C  w(46)=B+C+D+E  w(143)=C+D+E+F  w(240)=E+F+G
__device__ __constant__ int kSeg0[7] = {1, 47, 144, 228, 241, 274, 371};
__device__ __constant__ int kSeg1[7] = {46, 143, 227, 240, 273, 370, 467};
}

// K1: per (group, 128-col strip) compute the 7 disjoint segment sums of
// (S=x0+x1, Q=x0^2+x1^2) per column -- each x row read ONCE -- then the 4
// chunk-start window sums, written to snap[g][chunk][col] (2 MB in ws).
// Thread = (quad-in-strip q2, row-phase p of 16). Pure float4 streaming.
__global__ __launch_bounds__(512, 4) void lcn_snap(const float* __restrict__ x,
                                                   float2* __restrict__ snap) {
  const int B = blockIdx.x;
  const int g = B >> 2;              // 0..127
  const int st = B & 3;              // column strip (128 cols)
  const int w = threadIdx.x;
  const int q2 = w & 31;             // float4 quad within strip
  const int p = w >> 5;              // row phase 0..15

  const float* __restrict__ x0 = x + (size_t)(g * 2) * Hn * Wn;
  const float4* __restrict__ b0 =
      reinterpret_cast<const float4*>(x0) + st * 32 + q2;
  const float4* __restrict__ b1 = b0 + (size_t)Hn * (Wn / 4);

  float4 sgS[7], sgQ[7];
  #pragma unroll
  for (int s = 0; s < 7; ++s) {
    sgS[s] = make_float4(0.f, 0.f, 0.f, 0.f);
    sgQ[s] = make_float4(0.f, 0.f, 0.f, 0.f);
  }
  #pragma unroll
  for (int s = 0; s < 7; ++s) {
    for (int r = kSeg0[s] + p; r <= kSeg1[s]; r += 16) {
      float4 a = b0[(size_t)r * (Wn / 4)];
      float4 b = b1[(size_t)r * (Wn / 4)];
      sgS[s].x += a.x + b.x; sgQ[s].x += a.x * a.x + b.x * b.x;
      sgS[s].y += a.y + b.y; sgQ[s].y += a.y * a.y + b.y * b.y;
      sgS[s].z += a.z + b.z; sgQ[s].z += a.z * a.z + b.z * b.z;
      sgS[s].w += a.w + b.w; sgQ[s].w += a.w * a.w + b.w * b.w;
    }
  }

  // transpose: per segment, [16 phases][64 float4] -> per-col (S,Q)
  __shared__ float4 tbuf[16][64];    // 16 KB
  float2 sg[7];
  #pragma unroll
  for (int s = 0; s < 7; ++s) {
    __syncthreads();
    tbuf[p][2 * q2]     = make_float4(sgS[s].x, sgQ[s].x, sgS[s].y, sgQ[s].y);
    tbuf[p][2 * q2 + 1] = make_float4(sgS[s].z, sgQ[s].z, sgS[s].w, sgQ[s].w);
    __syncthreads();
    if (w < 128) {
      const float2* cf = reinterpret_cast<const float2*>(&tbuf[0][0]);
      float2 acc = {0.f, 0.f};
      #pragma unroll
      for (int pp = 0; pp < 16; ++pp) {
        float2 t = cf[pp * 128 + w];
        acc.x += t.x; acc.y += t.y;
      }
      sg[s] = acc;
    }
  }
  if (w < 128) {
    const float2 A = sg[0], Bs = sg[1], C = sg[2], D = sg[3],
                 E = sg[4], F = sg[5], G = sg[6];
    float2 w0 = {A.x + Bs.x + C.x, A.y + Bs.y + C.y};
    float2 w1 = {Bs.x + C.x + D.x + E.x, Bs.y + C.y + D.y + E.y};
    float2 w2 = {C.x + D.x + E.x + F.x, C.y + D.y + E.y + F.y};
    float2 w3 = {E.x + F.x + G.x, E.y + F.y + G.y};
    const size_t base = ((size_t)g * 4) * 512 + st * 128 + w;
    snap[base]            = w0;
    snap[base + 512]      = w1;
    snap[base + 2 * 512]  = w2;
    snap[base + 3 * 512]  = w3;
  }
}

// K2: fused slide+scan+normalize (round-8 structure, ramp REPLACED by the
// snapshot load; plain stores -- NT regressed in round 10).
// Phase B: per 8 stat rows: f32 vertical slide + 512-wide scan -> window
//          sums in Ps[buf]; normalize out rows hh = sh+113 directly.
// Phase C: chunk 0 streams border rows 0..112 (stat row 0), chunk 3 rows
//          398..511 (stat row 284), stats via bstat LDS.
// Window for stat (h,w): input rows h+1..h+227, cols w+1..w+227.
__global__ __launch_bounds__(512, 4) void lcn_fused(const float* __restrict__ x,
                                                    const float* __restrict__ weight,
                                                    const float* __restrict__ bias,
                                                    const float2* __restrict__ snap,
                                                    float* __restrict__ out) {
  const int B = blockIdx.x;
  const int X = B & 7;               // XCD (round-robin heuristic)
  const int s = B >> 3;
  const int chunk = s & 3;
  const int g = X * 16 + (s >> 2);   // 0..127 global group; chunks co-XCD
  const int w = threadIdx.x;
  const int lane = w & 63;
  const int wid = w >> 6;

  const float* __restrict__ x0 = x + (size_t)(g * 2) * Hn * Wn;
  const float* __restrict__ x1 = x0 + (size_t)Hn * Wn;
  float* __restrict__ o0 = out + (size_t)(g * 2) * Hn * Wn;
  float* __restrict__ o1 = o0 + (size_t)Hn * Wn;
  // weight/bias: 32 entries, index by channel within image (round-6 bug).
  const int cch = (g & 15) * 2;
  const float wt0 = weight[cch], wt1 = weight[cch + 1];
  const float bs0 = bias[cch], bs1 = bias[cch + 1];

  const int h0 = kH0[chunk];
  const int h1 = kH1[chunk];

  __shared__ __align__(16) float2 Ps[2][8][Wn + 1];  // double-buffered scans
  __shared__ float2 wsum[8][8];
  __shared__ float2 bstat[4][132];   // border stats, transposed [j][quad]

  // ---- chunk-start window sums from the snapshot (replaces the ramp) ----
  const float2 sv = snap[((size_t)(g * 4 + chunk)) * 512 + w];
  float accS = sv.x, accQ = sv.y;

  const float inv_n = 1.0f / (float)(WHn * WWn * 2);
  const int wp = min(max(w - PLn, 0), OWn - 1);   // out-col -> stat-col

  // slide prefetch: add rows h+228+j, sub rows h+1+j (j=0..7), 2 channels
  float pa0[8], pa1[8], ps0[8], ps1[8];
  auto prefetch = [&](int hb) {
    #pragma unroll
    for (int j = 0; j < 8; ++j) {
      int ra = min(hb + WHn + 1 + j, Hn - 1);   // clamp: guarded rows unused
      int rs = hb + 1 + j;                      // max 288 < 512
      pa0[j] = x0[(size_t)ra * Wn + w];
      pa1[j] = x1[(size_t)ra * Wn + w];
      ps0[j] = x0[(size_t)rs * Wn + w];
      ps1[j] = x1[(size_t)rs * Wn + w];
    }
  };
  prefetch(h0);

  // ---- Phase B: slide + scan + fused normalize, 8 rows/iter ----
  int buf = 0;
  for (int h = h0; h < h1; h += 8) {
    float2 v[8];
    v[0] = make_float2(accS, accQ);
    float s2 = accS, q2 = accQ;
    #pragma unroll
    for (int j = 0; j < 7; ++j) {
      s2 += (pa0[j] + pa1[j]) - (ps0[j] + ps1[j]);
      q2 += (pa0[j] * pa0[j] + pa1[j] * pa1[j])
          - (ps0[j] * ps0[j] + ps1[j] * ps1[j]);
      v[j + 1] = make_float2(s2, q2);
    }
    s2 += (pa0[7] + pa1[7]) - (ps0[7] + ps1[7]);
    q2 += (pa0[7] * pa0[7] + pa1[7] * pa1[7])
        - (ps0[7] * ps0[7] + ps1[7] * ps1[7]);
    accS = s2; accQ = q2;

    // issue next slide loads + this iteration's norm-x loads under the scan
    if (h + 8 < h1) prefetch(h + 8);
    float xa[8], xb[8];
    #pragma unroll
    for (int rr = 0; rr < 8; ++rr) {
      const size_t hh = (size_t)(h + PTn + rr) * Wn + w;  // max row 397+ < 512
      xa[rr] = x0[hh];
      xb[rr] = x1[hh];
    }

    // 8 independent 512-wide inclusive scans (shared barriers)
    #pragma unroll
    for (int d = 1; d < 64; d <<= 1) {
      #pragma unroll
      for (int rr = 0; rr < 8; ++rr) {
        float sx = __shfl_up(v[rr].x, d, 64);
        float sy = __shfl_up(v[rr].y, d, 64);
        if (lane >= d) { v[rr].x += sx; v[rr].y += sy; }
      }
    }
    if (lane == 63) {
      #pragma unroll
      for (int rr = 0; rr < 8; ++rr) wsum[wid][rr] = v[rr];
    }
    __syncthreads();
    float2 off[8] = {{0.f,0.f},{0.f,0.f},{0.f,0.f},{0.f,0.f},
                     {0.f,0.f},{0.f,0.f},{0.f,0.f},{0.f,0.f}};
    #pragma unroll
    for (int i = 0; i < 7; ++i) {
      if (i < wid) {
        #pragma unroll
        for (int rr = 0; rr < 8; ++rr) {
          off[rr].x += wsum[i][rr].x; off[rr].y += wsum[i][rr].y;
        }
      }
    }
    #pragma unroll
    for (int rr = 0; rr < 8; ++rr)
      Ps[buf][rr][w + 1] = make_float2(v[rr].x + off[rr].x, v[rr].y + off[rr].y);
    __syncthreads();

    // fused normalize: out row hh = (h+rr)+113 from stat row h+rr.
    #pragma unroll
    for (int rr = 0; rr < 8; ++rr) {
      if (h + rr < h1) {
        float2 hi = Ps[buf][rr][wp + WWn + 1];
        float2 lo = Ps[buf][rr][wp + 1];
        float S = hi.x - lo.x;
        float Q = hi.y - lo.y;
        float mean = S * inv_n;
        float var = (Q - S * S * inv_n) * inv_n;
        float istd = rsqrtf(var + EPSn);
        if ((chunk == 0 && h + rr == 0) || (chunk == 3 && h + rr == 284))
          bstat[w & 3][w >> 2] = make_float2(mean, istd);
        const size_t oo = (size_t)(h + PTn + rr) * Wn + w;
        o0[oo] = (xa[rr] - mean) * istd * wt0 + bs0;
        o1[oo] = (xb[rr] - mean) * istd * wt1 + bs1;
      }
    }
    buf ^= 1;
  }

  // ---- Phase C: replicate-pad border rows (chunk 0: 0..112, chunk 3: 398..511)
  if (chunk == 0 || chunk == 3) {
    __syncthreads();   // bstat visibility across threads
    const int row0 = (chunk == 0) ? 0 : 398;
    const int nrows = (chunk == 0) ? PTn : Hn - 398;   // 113 / 114
    const int total = nrows * 256;                     // 2 ch x 128 quads
    const float4* __restrict__ xf0 = reinterpret_cast<const float4*>(x0);
    const float4* __restrict__ xf1 = reinterpret_cast<const float4*>(x1);
    float4* __restrict__ of0 = reinterpret_cast<float4*>(o0);
    float4* __restrict__ of1 = reinterpret_cast<float4*>(o1);
    for (int i = w; i < total; i += 512) {
      const int qq = i & 127;
      const int ch = (i >> 7) & 1;
      const int row = row0 + (i >> 8);
      const size_t idx = (size_t)row * (Wn / 4) + qq;
      const float4 xv = ch ? xf1[idx] : xf0[idx];
      const float wt = ch ? wt1 : wt0;
      const float bsv = ch ? bs1 : bs0;
      const float2 m0 = bstat[0][qq];
      const float2 m1 = bstat[1][qq];
      const float2 m2 = bstat[2][qq];
      const float2 m3 = bstat[3][qq];
      float4 ov;
      ov.x = (xv.x - m0.x) * m0.y * wt + bsv;
      ov.y = (xv.y - m1.x) * m1.y * wt + bsv;
      ov.z = (xv.z - m2.x) * m2.y * wt + bsv;
      ov.w = (xv.w - m3.x) * m3.y * wt + bsv;
      if (ch) of1[idx] = ov; else of0[idx] = ov;
    }
  }
}

extern "C" void kernel_launch(void* const* d_in, const int* in_sizes, int n_in,
                              void* d_out, int out_size, void* d_ws, size_t ws_size,
                              hipStream_t stream) {
  const float* x = (const float*)d_in[0];
  const float* weight = (const float*)d_in[1];
  const float* bias = (const float*)d_in[2];
  float* out = (float*)d_out;
  float2* snap = (float2*)d_ws;   // 128*4*512*8 B = 2 MB (ws is far larger)

  hipLaunchKernelGGL(lcn_snap, dim3(512), dim3(512), 0, stream, x, snap);
  hipLaunchKernelGGL(lcn_fused, dim3(512), dim3(512), 0, stream,
                     x, weight, bias, snap, out);
}